// Round 26
// baseline (53.581 us; speedup 1.0000x reference)
//
#include <hip/hip_runtime.h>
#include <hip/hip_bf16.h>
#include <math.h>

// ---------------- problem constants ----------------
#define SEQ   4096
#define EMB   1024
#define NH    8
#define HD    128
#define NSLOT 15   // distinct gathered positions: 0..10, S-4..S-1 (+1 zero pad slot = 16)

typedef __attribute__((ext_vector_type(8))) short bf16x8;
typedef __attribute__((ext_vector_type(4))) float f32x4;
typedef __attribute__((ext_vector_type(4))) unsigned short ushort4v;
typedef unsigned short ushort_t;

// per-t slot multiplicity masks, 2 bits per slot (slot s at bits 2s..2s+1).
__device__ __constant__ unsigned int MULT[8] = {
    0x00005555u,  // t=0:   slots {0..7}
    0x10015055u,  // t=1:   {0,1,2,3,6,7,8,14}
    0x14050055u,  // t=2:   {0,1,2,3,8,9,13,14}
    0x15100055u,  // t=3:   {0,1,2,3,10,12,13,14}
    0x15800015u,  // t=S-3: {0,1,2, 11x2, 12,13,14}
    0x16800005u,  // t=S-2: {0,1, 11x2, 12x2, 13,14}
    0x1A800001u,  // t=S-1: {0, 11x2, 12x2, 13x2, 14}
    0x15400055u   // interior: {0,1,2,3,11,12,13,14}
};

__device__ __forceinline__ unsigned short f2bf(float x) {
    unsigned int u = __float_as_uint(x);
    return (unsigned short)((u + 0x7FFFu + ((u >> 16) & 1u)) >> 16);
}

// 8x fp32 -> bf16x8 via v_cvt_pk_bf16_f32 (RNE; no builtin on gfx950)
__device__ __forceinline__ bf16x8 cvt8(float4 a, float4 b) {
    union { unsigned int u[4]; bf16x8 v; } r;
    asm("v_cvt_pk_bf16_f32 %0, %1, %2" : "=v"(r.u[0]) : "v"(a.x), "v"(a.y));
    asm("v_cvt_pk_bf16_f32 %0, %1, %2" : "=v"(r.u[1]) : "v"(a.z), "v"(a.w));
    asm("v_cvt_pk_bf16_f32 %0, %1, %2" : "=v"(r.u[2]) : "v"(b.x), "v"(b.y));
    asm("v_cvt_pk_bf16_f32 %0, %1, %2" : "=v"(r.u[3]) : "v"(b.z), "v"(b.w));
    return r.v;
}

// bijective chunked XCD swizzle (nwg % 8 == 0)
__device__ __forceinline__ int xcd_swz(int bid, int nwg) {
    int cpx = nwg >> 3;
    return (bid & 7) * cpx + (bid >> 3);
}

// ---------------- small k/v projection (fp32): kvp[(b*2+kv)*15+slot][1024] ----------------
// R22-verbatim (broadcast weight reads)
__global__ __launch_bounds__(256) void proj_kv_small(
    const float* __restrict__ k, const float* __restrict__ v,
    const float* __restrict__ ipw, const float* __restrict__ ipb,
    float* __restrict__ kvp) {
    int fc  = blockIdx.x & 63;
    int bkv = blockIdx.x >> 6;
    int kv  = bkv & 1;
    int b   = bkv >> 1;

    const float* x0 = (kv ? v : k) + (size_t)b * SEQ * EMB;
    const float* Wm = ipw + (size_t)(1 + kv) * EMB * EMB;
    const float* bb = ipb + (size_t)(1 + kv) * EMB;

    __shared__ __align__(16) float xs[NSLOT][EMB + 4];   // +4 pad: 2-way banks only
    int tid = threadIdx.x;
#pragma unroll
    for (int i = 0; i < NSLOT; i++) {
        int pos = (i < 11) ? i : (SEQ - 4 + (i - 11));
        *(float4*)&xs[i][tid * 4] = *(const float4*)&x0[(size_t)pos * EMB + tid * 4];
    }
    __syncthreads();

    int row  = tid & 15;               // slot (15 -> idle)
    int feat = fc * 16 + (tid >> 4);
    if (row < NSLOT) {
        const float* wrow = Wm + (size_t)feat * EMB;
        float acc0 = 0.f, acc1 = 0.f;
#pragma unroll 4
        for (int kk = 0; kk < EMB; kk += 8) {
            float4 xv0 = *(const float4*)&xs[row][kk];
            float4 wv0 = *(const float4*)&wrow[kk];
            float4 xv1 = *(const float4*)&xs[row][kk + 4];
            float4 wv1 = *(const float4*)&wrow[kk + 4];
            acc0 += xv0.x * wv0.x + xv0.y * wv0.y + xv0.z * wv0.z + xv0.w * wv0.w;
            acc1 += xv1.x * wv1.x + xv1.y * wv1.y + xv1.z * wv1.z + xv1.w * wv1.w;
        }
        kvp[((size_t)((b * 2 + kv) * NSLOT + row)) * EMB + feat] = acc0 + acc1 + bb[feat];
    }
}

// ---------------- merged precompute: G2/cvec (gmat part) + UT2 (umat part) ----------------
// R23-verbatim. G2: [b][kc=k/8][hs][8]; UT2: [b][kc=hs/8][e][8].
union GUShared {
    struct { float xs[HD]; float red[HD]; } gm;
    float vs[NSLOT][256 + 4];
};
__global__ __launch_bounds__(256) void gu_pre(
    const float* __restrict__ kvp, const float* __restrict__ ipw,
    const float* __restrict__ ipb, const float* __restrict__ outw,
    ushort_t* __restrict__ G, float* __restrict__ cvec,
    ushort_t* __restrict__ UT, int nGm) {
    __shared__ __align__(16) GUShared sm;
    int tid = threadIdx.x;

    if (blockIdx.x < (unsigned)nGm) {
        // ---- gmat: G2[b][kc][hs][.] = (Wq_h^T kh_h[s])[k]; cvec = bq_h . kh_h[s] ----
        int hs = blockIdx.x & 127, b = blockIdx.x >> 7;
        int h = hs >> 4, s = hs & 15;
        if (tid < HD)
            sm.gm.xs[tid] = (s < NSLOT)
                ? kvp[((size_t)((b * 2 + 0) * NSLOT + s)) * EMB + h * HD + tid] : 0.f;
        __syncthreads();
        int e0 = tid * 4;
        float a0 = 0.f, a1 = 0.f, a2 = 0.f, a3 = 0.f;
#pragma unroll 8
        for (int d = 0; d < HD; d++) {
            float xv = sm.gm.xs[d];
            const float* wr_ = ipw + (size_t)(h * HD + d) * EMB + e0;
            a0 += xv * wr_[0]; a1 += xv * wr_[1]; a2 += xv * wr_[2]; a3 += xv * wr_[3];
        }
        ushort4v gv; gv[0] = f2bf(a0); gv[1] = f2bf(a1); gv[2] = f2bf(a2); gv[3] = f2bf(a3);
        int kc = e0 >> 3;
        *(ushort4v*)&G[(size_t)b * 131072 + kc * 1024 + hs * 8 + (e0 & 7)] = gv;

        if (tid < HD) sm.gm.red[tid] = sm.gm.xs[tid] * ipb[h * HD + tid];
        __syncthreads();
        if (tid < 64) {
            float vsum = sm.gm.red[tid] + sm.gm.red[tid + 64];
            vsum += __shfl_down(vsum, 32, 64); vsum += __shfl_down(vsum, 16, 64);
            vsum += __shfl_down(vsum, 8, 64);  vsum += __shfl_down(vsum, 4, 64);
            vsum += __shfl_down(vsum, 2, 64);  vsum += __shfl_down(vsum, 1, 64);
            if (tid == 0) cvec[b * 128 + hs] = vsum;
        }
    } else {
        // ---- umat: block = (ec, h-pair). UT2[b][hs/8][e][8] = vh_h[s].Wo[e,hHD..] ----
        int idx = blockIdx.x - nGm;
        int ec = idx & 63;
        int hp = (idx >> 6) & 3;
        int b  = idx >> 8;
        for (int i = tid; i < NSLOT * 64; i += 256) {
            int s_ = i >> 6, j4 = i & 63;
            *(float4*)&sm.vs[s_][j4 * 4] = *(const float4*)
                &kvp[((size_t)((b * 2 + 1) * NSLOT + s_)) * EMB + hp * 256 + j4 * 4];
        }
        __syncthreads();
        int s = tid & 15, el = tid >> 4;
        int e = ec * 16 + el;
#pragma unroll
        for (int hh = 0; hh < 2; hh++) {
            int h = hp * 2 + hh;
            float acc0 = 0.f, acc1 = 0.f;
            if (s < NSLOT) {
                const float* orow = outw + (size_t)e * EMB + h * HD;
                const float* vrow = &sm.vs[s][hh * 128];
#pragma unroll 4
                for (int d = 0; d < HD; d += 8) {
                    float4 o0 = *(const float4*)&orow[d];
                    float4 v0 = *(const float4*)&vrow[d];
                    float4 o1 = *(const float4*)&orow[d + 4];
                    float4 v1 = *(const float4*)&vrow[d + 4];
                    acc0 += o0.x * v0.x + o0.y * v0.y + o0.z * v0.z + o0.w * v0.w;
                    acc1 += o1.x * v1.x + o1.y * v1.y + o1.z * v1.z + o1.w * v1.w;
                }
            }
            int hs = h * 16 + s;
            UT[(size_t)b * 131072 + (hs >> 3) * 8192 + e * 8 + (hs & 7)]
                = f2bf(acc0 + acc1);
        }
    }
}

// ---------------- fused scores + softmax + output GEMM ----------------
// R25 structure + UT prefetch across the softmax barriers + __expf.
// Block = 16 t-rows, 512 threads (8 waves, wave = one head), grid 512.
#define TBM 16
#define NTQ 8
__global__ __launch_bounds__(512) void score_out(
    const float* __restrict__ q, const ushort_t* __restrict__ G,
    const float* __restrict__ cvec, const ushort_t* __restrict__ UT,
    const float* __restrict__ outb, float* __restrict__ out) {
    __shared__ __align__(16) union {
        ushort_t qbf[TBM * 1024];        // 32 KB
        ushort_t pl[TBM * 128];          // 4 KB
    } sm;

    int tid = threadIdx.x, lane = tid & 63, w = tid >> 6;   // w = head 0..7
    int fr = lane & 15, g = lane >> 4;
    int lb  = xcd_swz(blockIdx.x, gridDim.x);
    int mb0 = lb * TBM;
    int b   = mb0 >> 12;

    const ushort_t* Gb = G + (size_t)b * 131072;   // [kc][hs][8]
    int hsb = w * 16;                    // wave w covers head w (16 hs)
    float cv = cvec[b * 128 + hsb + fr];

    // ---- phase 0: q tile -> bf16 -> LDS. Wave w stages rows w*2, w*2+1.
#pragma unroll
    for (int r = 0; r < 2; r++) {
        int row = w * 2 + r;
        const float* qrp = q + (size_t)(mb0 + row) * EMB;
#pragma unroll
        for (int c = 0; c < 2; c++) {
            int k0 = c * 512 + lane * 8;
            float4 x0 = *(const float4*)(qrp + k0);
            float4 x1 = *(const float4*)(qrp + k0 + 4);
            bf16x8 vv = cvt8(x0, x1);
            int gi = k0 >> 3;
            int gs_ = (gi & ~15) | ((gi & 15) ^ row);
            *(bf16x8*)&sm.qbf[row * 1024 + gs_ * 8] = vv;
        }
    }
    __syncthreads();                     // publishes qbf

    // ---- phase 1: 4 independent MFMA chains over t in {0..7} ----
    f32x4 acc0 = {}, acc1 = {}, acc2 = {}, acc3 = {};
#pragma unroll
    for (int t = 0; t < NTQ; t += 4) {
        __builtin_amdgcn_s_setprio(1);
#pragma unroll
        for (int sub = 0; sub < 4; sub++) {
            int gi0 = (t + 0) * 16 + ((sub * 4 + g) ^ fr);
            bf16x8 af0 = *(const bf16x8*)&sm.qbf[fr * 1024 + gi0 * 8];
            int kc0 = (t + 0) * 16 + sub * 4 + g;
            bf16x8 bf0 = *(const bf16x8*)&Gb[((size_t)kc0 * 128 + hsb + fr) * 8];
            acc0 = __builtin_amdgcn_mfma_f32_16x16x32_bf16(af0, bf0, acc0, 0, 0, 0);

            int gi1 = (t + 1) * 16 + ((sub * 4 + g) ^ fr);
            bf16x8 af1 = *(const bf16x8*)&sm.qbf[fr * 1024 + gi1 * 8];
            int kc1 = (t + 1) * 16 + sub * 4 + g;
            bf16x8 bf1 = *(const bf16x8*)&Gb[((size_t)kc1 * 128 + hsb + fr) * 8];
            acc1 = __builtin_amdgcn_mfma_f32_16x16x32_bf16(af1, bf1, acc1, 0, 0, 0);

            int gi2 = (t + 2) * 16 + ((sub * 4 + g) ^ fr);
            bf16x8 af2 = *(const bf16x8*)&sm.qbf[fr * 1024 + gi2 * 8];
            int kc2 = (t + 2) * 16 + sub * 4 + g;
            bf16x8 bf2 = *(const bf16x8*)&Gb[((size_t)kc2 * 128 + hsb + fr) * 8];
            acc2 = __builtin_amdgcn_mfma_f32_16x16x32_bf16(af2, bf2, acc2, 0, 0, 0);

            int gi3 = (t + 3) * 16 + ((sub * 4 + g) ^ fr);
            bf16x8 af3 = *(const bf16x8*)&sm.qbf[fr * 1024 + gi3 * 8];
            int kc3 = (t + 3) * 16 + sub * 4 + g;
            bf16x8 bf3 = *(const bf16x8*)&Gb[((size_t)kc3 * 128 + hsb + fr) * 8];
            acc3 = __builtin_amdgcn_mfma_f32_16x16x32_bf16(af3, bf3, acc3, 0, 0, 0);
        }
        __builtin_amdgcn_s_setprio(0);
    }
    f32x4 acc = (acc0 + acc1) + (acc2 + acc3);

    // ---- prefetch first 8 UT B-fragments (independent of P; in flight across
    // barriers + softmax — compiler can't hoist loads past __syncthreads itself)
    const ushort_t* UTb = UT + (size_t)b * 131072;   // [kc][e][8]
    int eb = w * 128;
    bf16x8 ubp[8];
#pragma unroll
    for (int n = 0; n < 2; n++)
#pragma unroll
        for (int kk = 0; kk < 4; kk++) {
            int gi = kk * 4 + g;
            ubp[n * 4 + kk] =
                *(const bf16x8*)&UTb[((size_t)gi * 1024 + (eb + n * 16 + fr)) * 8];
        }

    __syncthreads();   // all qbf reads done before pl-union overwrite

    // ---- softmax (per (t, head=w) over 16 slots = 16 lanes) -> P in LDS ----
    const float scale = 0.08838834764831845f;   // 1/sqrt(128)
#pragma unroll
    for (int r = 0; r < 4; r++) {
        int row = g * 4 + r;
        int tl  = (mb0 + row) & (SEQ - 1);
        int cse = (tl >= 4 && tl <= SEQ - 4) ? 7 : ((tl < 4) ? tl : tl - (SEQ - 3) + 4);
        float mult = (float)((MULT[cse] >> (fr * 2)) & 3u);
        float vv = (acc[r] + cv) * scale;
        float vm = (mult != 0.f) ? vv : -1e30f;
#pragma unroll
        for (int sh = 1; sh < 16; sh <<= 1) vm = fmaxf(vm, __shfl_xor(vm, sh, 64));
        float e_ = mult * __expf(vv - vm);
        float z = e_;
#pragma unroll
        for (int sh = 1; sh < 16; sh <<= 1) z += __shfl_xor(z, sh, 64);
        int col = hsb + fr;
        int cg  = col >> 3;
        int pg  = (cg & 8) | ((cg & 7) ^ (row & 7));   // granule XOR swizzle
        sm.pl[row * 128 + pg * 8 + (col & 7)] = f2bf(e_ / z);
    }
    __syncthreads();

    // ---- phase 2: out(16 rows x 128 e per wave) = P @ UT2^T + outb ----
#pragma unroll
    for (int n = 0; n < 8; n++) {
        int e = eb + n * 16 + fr;
        f32x4 o2 = {};
#pragma unroll
        for (int kk = 0; kk < 4; kk++) {
            int gi = kk * 4 + g;
            bf16x8 ub = (n < 2) ? ubp[n * 4 + kk]
                                : *(const bf16x8*)&UTb[((size_t)gi * 1024 + e) * 8];
            int pg = (gi & 8) | ((gi & 7) ^ (fr & 7));
            bf16x8 pa = *(const bf16x8*)&sm.pl[fr * 128 + pg * 8];
            o2 = __builtin_amdgcn_mfma_f32_16x16x32_bf16(pa, ub, o2, 0, 0, 0);
        }
        float bn = outb[e];
#pragma unroll
        for (int r = 0; r < 4; r++)
            out[(size_t)(mb0 + g * 4 + r) * EMB + e] = o2[r] + bn;
    }
}

// ---------------- launcher ----------------
extern "C" void kernel_launch(void* const* d_in, const int* in_sizes, int n_in,
                              void* d_out, int out_size, void* d_ws, size_t ws_size,
                              hipStream_t stream) {
    const float* q    = (const float*)d_in[0];
    const float* k    = (const float*)d_in[1];
    const float* v    = (const float*)d_in[2];
    const float* ipw  = (const float*)d_in[3];
    const float* ipb  = (const float*)d_in[4];
    const float* outw = (const float*)d_in[5];
    const float* outb = (const float*)d_in[6];
    float* out = (float*)d_out;

    int Bb = in_sizes[0] / (SEQ * EMB);     // batch (=2)
    int M  = Bb * SEQ;                      // 8192

    float*    kvp  = (float*)d_ws;                                     // Bb*2*15*1024 f32
    ushort_t* G    = (ushort_t*)(kvp + (size_t)Bb * 2 * NSLOT * EMB);  // Bb*131072 bf16 (kc-major)
    ushort_t* UTm  = G + (size_t)Bb * 131072;                          // Bb*131072 bf16 (kc-major)
    float*    cvec = (float*)(UTm + (size_t)Bb * 131072);              // Bb*128 f32

    proj_kv_small<<<dim3(Bb * 2 * 64), dim3(256), 0, stream>>>(k, v, ipw, ipb, kvp);
    gu_pre<<<dim3(Bb * 128 + Bb * 256), dim3(256), 0, stream>>>(
        kvp, ipw, ipb, outw, G, cvec, UTm, Bb * 128);
    score_out<<<dim3(M / TBM), dim3(512), 0, stream>>>(q, G, cvec, UTm, outb, out);
}

// Round 28
// 53.481 us; speedup vs baseline: 1.0019x; 1.0019x over previous
//
#include <hip/hip_runtime.h>
#include <hip/hip_bf16.h>
#include <math.h>

// ---------------- problem constants ----------------
#define SEQ   4096
#define EMB   1024
#define NH    8
#define HD    128
#define NSLOT 15   // distinct gathered positions: 0..10, S-4..S-1 (+1 zero pad slot = 16)

typedef __attribute__((ext_vector_type(8))) short bf16x8;
typedef __attribute__((ext_vector_type(4))) float f32x4;
typedef __attribute__((ext_vector_type(4))) unsigned short ushort4v;
typedef unsigned short ushort_t;

// per-t slot multiplicity masks, 2 bits per slot (slot s at bits 2s..2s+1).
__device__ __constant__ unsigned int MULT[8] = {
    0x00005555u,  // t=0:   slots {0..7}
    0x10015055u,  // t=1:   {0,1,2,3,6,7,8,14}
    0x14050055u,  // t=2:   {0,1,2,3,8,9,13,14}
    0x15100055u,  // t=3:   {0,1,2,3,10,12,13,14}
    0x15800015u,  // t=S-3: {0,1,2, 11x2, 12,13,14}
    0x16800005u,  // t=S-2: {0,1, 11x2, 12x2, 13,14}
    0x1A800001u,  // t=S-1: {0, 11x2, 12x2, 13x2, 14}
    0x15400055u   // interior: {0,1,2,3,11,12,13,14}
};

__device__ __forceinline__ unsigned short f2bf(float x) {
    unsigned int u = __float_as_uint(x);
    return (unsigned short)((u + 0x7FFFu + ((u >> 16) & 1u)) >> 16);
}

// 8x fp32 -> bf16x8 via v_cvt_pk_bf16_f32 (RNE; no builtin on gfx950)
__device__ __forceinline__ bf16x8 cvt8(float4 a, float4 b) {
    union { unsigned int u[4]; bf16x8 v; } r;
    asm("v_cvt_pk_bf16_f32 %0, %1, %2" : "=v"(r.u[0]) : "v"(a.x), "v"(a.y));
    asm("v_cvt_pk_bf16_f32 %0, %1, %2" : "=v"(r.u[1]) : "v"(a.z), "v"(a.w));
    asm("v_cvt_pk_bf16_f32 %0, %1, %2" : "=v"(r.u[2]) : "v"(b.x), "v"(b.y));
    asm("v_cvt_pk_bf16_f32 %0, %1, %2" : "=v"(r.u[3]) : "v"(b.z), "v"(b.w));
    return r.v;
}

// bijective chunked XCD swizzle (nwg % 8 == 0)
__device__ __forceinline__ int xcd_swz(int bid, int nwg) {
    int cpx = nwg >> 3;
    return (bid & 7) * cpx + (bid >> 3);
}

// ---------------- small k/v projection (fp32): kvp[(b*2+kv)*15+slot][1024] ----------------
// broadcast weight reads (R22-proven)
__global__ __launch_bounds__(256) void proj_kv_small(
    const float* __restrict__ k, const float* __restrict__ v,
    const float* __restrict__ ipw, const float* __restrict__ ipb,
    float* __restrict__ kvp) {
    int fc  = blockIdx.x & 63;
    int bkv = blockIdx.x >> 6;
    int kv  = bkv & 1;
    int b   = bkv >> 1;

    const float* x0 = (kv ? v : k) + (size_t)b * SEQ * EMB;
    const float* Wm = ipw + (size_t)(1 + kv) * EMB * EMB;
    const float* bb = ipb + (size_t)(1 + kv) * EMB;

    __shared__ __align__(16) float xs[NSLOT][EMB + 4];   // +4 pad: 2-way banks only
    int tid = threadIdx.x;
#pragma unroll
    for (int i = 0; i < NSLOT; i++) {
        int pos = (i < 11) ? i : (SEQ - 4 + (i - 11));
        *(float4*)&xs[i][tid * 4] = *(const float4*)&x0[(size_t)pos * EMB + tid * 4];
    }
    __syncthreads();

    int row  = tid & 15;               // slot (15 -> idle)
    int feat = fc * 16 + (tid >> 4);
    if (row < NSLOT) {
        const float* wrow = Wm + (size_t)feat * EMB;
        float acc0 = 0.f, acc1 = 0.f;
#pragma unroll 4
        for (int kk = 0; kk < EMB; kk += 8) {
            float4 xv0 = *(const float4*)&xs[row][kk];
            float4 wv0 = *(const float4*)&wrow[kk];
            float4 xv1 = *(const float4*)&xs[row][kk + 4];
            float4 wv1 = *(const float4*)&wrow[kk + 4];
            acc0 += xv0.x * wv0.x + xv0.y * wv0.y + xv0.z * wv0.z + xv0.w * wv0.w;
            acc1 += xv1.x * wv1.x + xv1.y * wv1.y + xv1.z * wv1.z + xv1.w * wv1.w;
        }
        kvp[((size_t)((b * 2 + kv) * NSLOT + row)) * EMB + feat] = acc0 + acc1 + bb[feat];
    }
}

// ---------------- merged precompute: G2/cvec (gmat part) + UT2 (umat part) ----------------
// G2: [b][kc=k/8][hs][8]; UT2: [b][kc=hs/8][e][8]  (k-chunk-major for coalesced B-frags)
union GUShared {
    struct { float xs[HD]; float red[HD]; } gm;
    float vs[NSLOT][256 + 4];
};
__global__ __launch_bounds__(256) void gu_pre(
    const float* __restrict__ kvp, const float* __restrict__ ipw,
    const float* __restrict__ ipb, const float* __restrict__ outw,
    ushort_t* __restrict__ G, float* __restrict__ cvec,
    ushort_t* __restrict__ UT, int nGm) {
    __shared__ __align__(16) GUShared sm;
    int tid = threadIdx.x;

    if (blockIdx.x < (unsigned)nGm) {
        // ---- gmat: G2[b][kc][hs][.] = (Wq_h^T kh_h[s])[k]; cvec = bq_h . kh_h[s] ----
        int hs = blockIdx.x & 127, b = blockIdx.x >> 7;
        int h = hs >> 4, s = hs & 15;
        if (tid < HD)
            sm.gm.xs[tid] = (s < NSLOT)
                ? kvp[((size_t)((b * 2 + 0) * NSLOT + s)) * EMB + h * HD + tid] : 0.f;
        __syncthreads();
        int e0 = tid * 4;
        float a0 = 0.f, a1 = 0.f, a2 = 0.f, a3 = 0.f;
#pragma unroll 8
        for (int d = 0; d < HD; d++) {
            float xv = sm.gm.xs[d];
            const float* wr_ = ipw + (size_t)(h * HD + d) * EMB + e0;
            a0 += xv * wr_[0]; a1 += xv * wr_[1]; a2 += xv * wr_[2]; a3 += xv * wr_[3];
        }
        ushort4v gv; gv[0] = f2bf(a0); gv[1] = f2bf(a1); gv[2] = f2bf(a2); gv[3] = f2bf(a3);
        int kc = e0 >> 3;
        *(ushort4v*)&G[(size_t)b * 131072 + kc * 1024 + hs * 8 + (e0 & 7)] = gv;

        if (tid < HD) sm.gm.red[tid] = sm.gm.xs[tid] * ipb[h * HD + tid];
        __syncthreads();
        if (tid < 64) {
            float vsum = sm.gm.red[tid] + sm.gm.red[tid + 64];
            vsum += __shfl_down(vsum, 32, 64); vsum += __shfl_down(vsum, 16, 64);
            vsum += __shfl_down(vsum, 8, 64);  vsum += __shfl_down(vsum, 4, 64);
            vsum += __shfl_down(vsum, 2, 64);  vsum += __shfl_down(vsum, 1, 64);
            if (tid == 0) cvec[b * 128 + hs] = vsum;
        }
    } else {
        // ---- umat: block = (ec, h-pair). UT2[b][hs/8][e][8] = vh_h[s].Wo[e,hHD..] ----
        int idx = blockIdx.x - nGm;
        int ec = idx & 63;
        int hp = (idx >> 6) & 3;
        int b  = idx >> 8;
        for (int i = tid; i < NSLOT * 64; i += 256) {
            int s_ = i >> 6, j4 = i & 63;
            *(float4*)&sm.vs[s_][j4 * 4] = *(const float4*)
                &kvp[((size_t)((b * 2 + 1) * NSLOT + s_)) * EMB + hp * 256 + j4 * 4];
        }
        __syncthreads();
        int s = tid & 15, el = tid >> 4;
        int e = ec * 16 + el;
#pragma unroll
        for (int hh = 0; hh < 2; hh++) {
            int h = hp * 2 + hh;
            float acc0 = 0.f, acc1 = 0.f;
            if (s < NSLOT) {
                const float* orow = outw + (size_t)e * EMB + h * HD;
                const float* vrow = &sm.vs[s][hh * 128];
#pragma unroll 4
                for (int d = 0; d < HD; d += 8) {
                    float4 o0 = *(const float4*)&orow[d];
                    float4 v0 = *(const float4*)&vrow[d];
                    float4 o1 = *(const float4*)&orow[d + 4];
                    float4 v1 = *(const float4*)&vrow[d + 4];
                    acc0 += o0.x * v0.x + o0.y * v0.y + o0.z * v0.z + o0.w * v0.w;
                    acc1 += o1.x * v1.x + o1.y * v1.y + o1.z * v1.z + o1.w * v1.w;
                }
            }
            int hs = h * 16 + s;
            UT[(size_t)b * 131072 + (hs >> 3) * 8192 + e * 8 + (hs & 7)]
                = f2bf(acc0 + acc1);
        }
    }
}

// ---------------- fused scores + softmax + output GEMM ----------------
// Block = 16 t-rows, 512 threads (8 waves, wave = one head), grid 512.
// Phase 0: q -> bf16 -> LDS once. Phase 1: barrier-free, G2 coalesced, 4 chains.
// UT prefetch across softmax barriers. Phase 2: UT2 kc-major coalesced.
#define TBM 16
#define NTQ 8
__global__ __launch_bounds__(512) void score_out(
    const float* __restrict__ q, const ushort_t* __restrict__ G,
    const float* __restrict__ cvec, const ushort_t* __restrict__ UT,
    const float* __restrict__ outb, float* __restrict__ out) {
    __shared__ __align__(16) union {
        ushort_t qbf[TBM * 1024];        // 32 KB
        ushort_t pl[TBM * 128];          // 4 KB
    } sm;

    int tid = threadIdx.x, lane = tid & 63, w = tid >> 6;   // w = head 0..7
    int fr = lane & 15, g = lane >> 4;
    int lb  = xcd_swz(blockIdx.x, gridDim.x);
    int mb0 = lb * TBM;
    int b   = mb0 >> 12;

    const ushort_t* Gb = G + (size_t)b * 131072;   // [kc][hs][8]
    int hsb = w * 16;                    // wave w covers head w (16 hs)
    float cv = cvec[b * 128 + hsb + fr];

    // ---- phase 0: q tile -> bf16 -> LDS. Wave w stages rows w*2, w*2+1.
#pragma unroll
    for (int r = 0; r < 2; r++) {
        int row = w * 2 + r;
        const float* qrp = q + (size_t)(mb0 + row) * EMB;
#pragma unroll
        for (int c = 0; c < 2; c++) {
            int k0 = c * 512 + lane * 8;
            float4 x0 = *(const float4*)(qrp + k0);
            float4 x1 = *(const float4*)(qrp + k0 + 4);
            bf16x8 vv = cvt8(x0, x1);
            int gi = k0 >> 3;
            int gs_ = (gi & ~15) | ((gi & 15) ^ row);
            *(bf16x8*)&sm.qbf[row * 1024 + gs_ * 8] = vv;
        }
    }
    __syncthreads();                     // publishes qbf

    // ---- phase 1: 4 independent MFMA chains over t in {0..7} ----
    f32x4 acc0 = {}, acc1 = {}, acc2 = {}, acc3 = {};
#pragma unroll
    for (int t = 0; t < NTQ; t += 4) {
        __builtin_amdgcn_s_setprio(1);
#pragma unroll
        for (int sub = 0; sub < 4; sub++) {
            int gi0 = (t + 0) * 16 + ((sub * 4 + g) ^ fr);
            bf16x8 af0 = *(const bf16x8*)&sm.qbf[fr * 1024 + gi0 * 8];
            int kc0 = (t + 0) * 16 + sub * 4 + g;
            bf16x8 bf0 = *(const bf16x8*)&Gb[((size_t)kc0 * 128 + hsb + fr) * 8];
            acc0 = __builtin_amdgcn_mfma_f32_16x16x32_bf16(af0, bf0, acc0, 0, 0, 0);

            int gi1 = (t + 1) * 16 + ((sub * 4 + g) ^ fr);
            bf16x8 af1 = *(const bf16x8*)&sm.qbf[fr * 1024 + gi1 * 8];
            int kc1 = (t + 1) * 16 + sub * 4 + g;
            bf16x8 bf1 = *(const bf16x8*)&Gb[((size_t)kc1 * 128 + hsb + fr) * 8];
            acc1 = __builtin_amdgcn_mfma_f32_16x16x32_bf16(af1, bf1, acc1, 0, 0, 0);

            int gi2 = (t + 2) * 16 + ((sub * 4 + g) ^ fr);
            bf16x8 af2 = *(const bf16x8*)&sm.qbf[fr * 1024 + gi2 * 8];
            int kc2 = (t + 2) * 16 + sub * 4 + g;
            bf16x8 bf2 = *(const bf16x8*)&Gb[((size_t)kc2 * 128 + hsb + fr) * 8];
            acc2 = __builtin_amdgcn_mfma_f32_16x16x32_bf16(af2, bf2, acc2, 0, 0, 0);

            int gi3 = (t + 3) * 16 + ((sub * 4 + g) ^ fr);
            bf16x8 af3 = *(const bf16x8*)&sm.qbf[fr * 1024 + gi3 * 8];
            int kc3 = (t + 3) * 16 + sub * 4 + g;
            bf16x8 bf3 = *(const bf16x8*)&Gb[((size_t)kc3 * 128 + hsb + fr) * 8];
            acc3 = __builtin_amdgcn_mfma_f32_16x16x32_bf16(af3, bf3, acc3, 0, 0, 0);
        }
        __builtin_amdgcn_s_setprio(0);
    }
    f32x4 acc = (acc0 + acc1) + (acc2 + acc3);

    // ---- prefetch first 8 UT B-fragments (independent of P; in flight across
    // barriers + softmax)
    const ushort_t* UTb = UT + (size_t)b * 131072;   // [kc][e][8]
    int eb = w * 128;
    bf16x8 ubp[8];
#pragma unroll
    for (int n = 0; n < 2; n++)
#pragma unroll
        for (int kk = 0; kk < 4; kk++) {
            int gi = kk * 4 + g;
            ubp[n * 4 + kk] =
                *(const bf16x8*)&UTb[((size_t)gi * 1024 + (eb + n * 16 + fr)) * 8];
        }

    __syncthreads();   // all qbf reads done before pl-union overwrite

    // ---- softmax (per (t, head=w) over 16 slots = 16 lanes) -> P in LDS ----
    const float scale = 0.08838834764831845f;   // 1/sqrt(128)
#pragma unroll
    for (int r = 0; r < 4; r++) {
        int row = g * 4 + r;
        int tl  = (mb0 + row) & (SEQ - 1);
        int cse = (tl >= 4 && tl <= SEQ - 4) ? 7 : ((tl < 4) ? tl : tl - (SEQ - 3) + 4);
        float mult = (float)((MULT[cse] >> (fr * 2)) & 3u);
        float vv = (acc[r] + cv) * scale;
        float vm = (mult != 0.f) ? vv : -1e30f;
#pragma unroll
        for (int sh = 1; sh < 16; sh <<= 1) vm = fmaxf(vm, __shfl_xor(vm, sh, 64));
        float e_ = mult * __expf(vv - vm);
        float z = e_;
#pragma unroll
        for (int sh = 1; sh < 16; sh <<= 1) z += __shfl_xor(z, sh, 64);
        int col = hsb + fr;
        int cg  = col >> 3;
        int pg  = (cg & 8) | ((cg & 7) ^ (row & 7));   // granule XOR swizzle
        sm.pl[row * 128 + pg * 8 + (col & 7)] = f2bf(e_ / z);
    }
    __syncthreads();

    // ---- phase 2: out(16 rows x 128 e per wave) = P @ UT2^T + outb ----
#pragma unroll
    for (int n = 0; n < 8; n++) {
        int e = eb + n * 16 + fr;
        f32x4 o2 = {};
#pragma unroll
        for (int kk = 0; kk < 4; kk++) {
            int gi = kk * 4 + g;
            bf16x8 ub = (n < 2) ? ubp[n * 4 + kk]
                                : *(const bf16x8*)&UTb[((size_t)gi * 1024 + e) * 8];
            int pg = (gi & 8) | ((gi & 7) ^ (fr & 7));
            bf16x8 pa = *(const bf16x8*)&sm.pl[fr * 128 + pg * 8];
            o2 = __builtin_amdgcn_mfma_f32_16x16x32_bf16(pa, ub, o2, 0, 0, 0);
        }
        float bn = outb[e];
#pragma unroll
        for (int r = 0; r < 4; r++)
            out[(size_t)(mb0 + g * 4 + r) * EMB + e] = o2[r] + bn;
    }
}

// ---------------- launcher ----------------
extern "C" void kernel_launch(void* const* d_in, const int* in_sizes, int n_in,
                              void* d_out, int out_size, void* d_ws, size_t ws_size,
                              hipStream_t stream) {
    const float* q    = (const float*)d_in[0];
    const float* k    = (const float*)d_in[1];
    const float* v    = (const float*)d_in[2];
    const float* ipw  = (const float*)d_in[3];
    const float* ipb  = (const float*)d_in[4];
    const float* outw = (const float*)d_in[5];
    const float* outb = (const float*)d_in[6];
    float* out = (float*)d_out;

    int Bb = in_sizes[0] / (SEQ * EMB);     // batch (=2)
    int M  = Bb * SEQ;                      // 8192

    float*    kvp  = (float*)d_ws;                                     // Bb*2*15*1024 f32
    ushort_t* G    = (ushort_t*)(kvp + (size_t)Bb * 2 * NSLOT * EMB);  // Bb*131072 bf16 (kc-major)
    ushort_t* UTm  = G + (size_t)Bb * 131072;                          // Bb*131072 bf16 (kc-major)
    float*    cvec = (float*)(UTm + (size_t)Bb * 131072);              // Bb*128 f32

    proj_kv_small<<<dim3(Bb * 2 * 64), dim3(256), 0, stream>>>(k, v, ipw, ipb, kvp);
    gu_pre<<<dim3(Bb * 128 + Bb * 256), dim3(256), 0, stream>>>(
        kvp, ipw, ipb, outw, G, cvec, UTm, Bb * 128);
    score_out<<<dim3(M / TBM), dim3(512), 0, stream>>>(q, G, cvec, UTm, outb, out);
}